// Round 15
// baseline (596.564 us; speedup 1.0000x reference)
//
#include <hip/hip_runtime.h>
#include <stdint.h>

// ---------- helpers ----------
typedef __attribute__((ext_vector_type(8))) short short8;   // 8 x bf16 (4 VGPRs)
typedef __attribute__((ext_vector_type(4))) float floatx4;  // MFMA accum

__device__ __forceinline__ unsigned short f2bf(float f) {
  union { float f; unsigned int u; } c; c.f = f;
  unsigned int u = c.u;
  unsigned int r = (u + 0x7fffu + ((u >> 16) & 1u)) >> 16;  // RNE
  return (unsigned short)r;
}

// async global->LDS, 16B per lane. LDS dest is wave-uniform base + lane*16.
__device__ __forceinline__ void load16_to_lds(const void* g, void* l) {
  __builtin_amdgcn_global_load_lds(
      (const __attribute__((address_space(1))) unsigned int*)g,
      (__attribute__((address_space(3))) unsigned int*)l, 16, 0, 0);
}

// ---------- elementwise kernels ----------
__global__ void f32_to_bf16_kernel(const float* __restrict__ in,
                                   unsigned short* __restrict__ out, long n4) {
  long i = blockIdx.x * (long)blockDim.x + threadIdx.x;
  if (i >= n4) return;
  float4 v = ((const float4*)in)[i];
  ushort4 o;
  o.x = f2bf(v.x); o.y = f2bf(v.y); o.z = f2bf(v.z); o.w = f2bf(v.w);
  ((ushort4*)out)[i] = o;
}

__global__ void dequant2_kernel(const float* __restrict__ w1q,
                                const float* __restrict__ s1,
                                const float* __restrict__ w3q,
                                const float* __restrict__ s3,
                                unsigned short* __restrict__ o1,
                                unsigned short* __restrict__ o3,
                                int K, int sK) {
  int n = blockIdx.y;
  int k = blockIdx.x * 1024 + threadIdx.x * 4;
  size_t idx = (size_t)n * K + k;
  int sidx = (n >> 7) * sK + (k >> 7);
  float sc1 = s1[sidx], sc3 = s3[sidx];
  float4 v1 = *(const float4*)(w1q + idx);
  float4 v3 = *(const float4*)(w3q + idx);
  ushort4 a, b;
  a.x = f2bf(v1.x * sc1); a.y = f2bf(v1.y * sc1);
  a.z = f2bf(v1.z * sc1); a.w = f2bf(v1.w * sc1);
  b.x = f2bf(v3.x * sc3); b.y = f2bf(v3.y * sc3);
  b.z = f2bf(v3.z * sc3); b.w = f2bf(v3.w * sc3);
  *(ushort4*)(o1 + idx) = a;
  *(ushort4*)(o3 + idx) = b;
}

__global__ void dequant1_kernel(const float* __restrict__ wq,
                                const float* __restrict__ s,
                                unsigned short* __restrict__ out,
                                int K, int sK) {
  int n = blockIdx.y;
  int k = blockIdx.x * 1024 + threadIdx.x * 4;
  size_t idx = (size_t)n * K + k;
  float sc = s[(n >> 7) * sK + (k >> 7)];
  float4 v = *(const float4*)(wq + idx);
  ushort4 o;
  o.x = f2bf(v.x * sc); o.y = f2bf(v.y * sc);
  o.z = f2bf(v.z * sc); o.w = f2bf(v.w * sc);
  *(ushort4*)(out + idx) = o;
}

// ---------- merged dual GEMM + silu (proven: 269-272 us, 39% MfmaUtil) ----------
// Register-bound at 2 blocks/CU (acc 128 + frags ~48 unified regs); no
// residency lever exists here -- do not touch (R9's (256,3) spilled: 560us).
__global__ __launch_bounds__(256, 2) void dual_gemm_silu(
    const unsigned short* __restrict__ A,   // [M,K] bf16 (x)
    const unsigned short* __restrict__ B1,  // [N,K] bf16 (w1)
    const unsigned short* __restrict__ B3,  // [N,K] bf16 (w3)
    unsigned short* __restrict__ C,         // [M,N] bf16 fused
    int M, int N, int K) {
  __shared__ unsigned short As[128 * 64];   // 16 KB
  __shared__ unsigned short B1s[128 * 64];  // 16 KB
  __shared__ unsigned short B3s[128 * 64];  // 16 KB

  const int tid = threadIdx.x;
  const int lane = tid & 63;
  const int wave = tid >> 6;      // 0..3
  const int wm = wave >> 1;       // 0..1  (M 64-half)
  const int wn = wave & 1;        // 0..1  (N 64-half)
  const int m0 = blockIdx.y * 128, n0 = blockIdx.x * 128;

  int soff[4];
  int sdst[4];
#pragma unroll
  for (int p = 0; p < 4; p++) {
    int u = tid + 256 * p;
    int r = u >> 3;
    int c = ((u & 7) ^ (r & 7)) * 8;
    soff[p] = r * K + c;   // pre-swizzled global source
    sdst[p] = u * 8;       // linear LDS dest
  }

  const int q = lane >> 4;        // 0..3
  const int r16 = lane & 15;
  const int rx = r16 & 7;

  floatx4 acc_g[4][4], acc_u[4][4];
#pragma unroll
  for (int i = 0; i < 4; i++)
#pragma unroll
    for (int j = 0; j < 4; j++) {
      acc_g[i][j] = (floatx4){0.f, 0.f, 0.f, 0.f};
      acc_u[i][j] = (floatx4){0.f, 0.f, 0.f, 0.f};
    }

  const unsigned short* Abase = A + (size_t)m0 * K;
  const unsigned short* B1base = B1 + (size_t)n0 * K;
  const unsigned short* B3base = B3 + (size_t)n0 * K;

  for (int k0 = 0; k0 < K; k0 += 64) {
#pragma unroll
    for (int p = 0; p < 4; p++) {
      load16_to_lds(Abase + soff[p] + k0, &As[sdst[p]]);
      load16_to_lds(B1base + soff[p] + k0, &B1s[sdst[p]]);
      load16_to_lds(B3base + soff[p] + k0, &B3s[sdst[p]]);
    }
    __syncthreads();

#pragma unroll
    for (int kh = 0; kh < 2; kh++) {
      const int kq = kh * 4 + q;          // kblk 0..7
      short8 a[4], b1v[4], b3v[4];
#pragma unroll
      for (int t = 0; t < 4; t++) {
        int row = wm * 64 + t * 16 + r16;
        a[t] = *(const short8*)&As[(row * 8 + (kq ^ rx)) * 8];
      }
#pragma unroll
      for (int j = 0; j < 4; j++) {
        int row = wn * 64 + j * 16 + r16;
        int u = (row * 8 + (kq ^ rx)) * 8;
        b1v[j] = *(const short8*)&B1s[u];
        b3v[j] = *(const short8*)&B3s[u];
      }
#pragma unroll
      for (int i = 0; i < 4; i++)
#pragma unroll
        for (int j = 0; j < 4; j++) {
          acc_g[i][j] = __builtin_amdgcn_mfma_f32_16x16x32_bf16(
              a[i], b1v[j], acc_g[i][j], 0, 0, 0);
          acc_u[i][j] = __builtin_amdgcn_mfma_f32_16x16x32_bf16(
              a[i], b3v[j], acc_u[i][j], 0, 0, 0);
        }
    }
    __syncthreads();
  }

#pragma unroll
  for (int i = 0; i < 4; i++) {
    int row0 = m0 + wm * 64 + i * 16 + q * 4;
#pragma unroll
    for (int j = 0; j < 4; j++) {
      int col = n0 + wn * 64 + j * 16 + r16;
#pragma unroll
      for (int rr = 0; rr < 4; rr++) {
        float gv = acc_g[i][j][rr];
        float uv = acc_u[i][j][rr];
        float sv = gv / (1.f + __expf(-gv)) * uv;
        C[(size_t)(row0 + rr) * N + col] = f2bf(sv);
      }
    }
  }
}

// ---------- GEMM2: R0-proven 128^2 body + split-K=2 for residency ----------
// Residency model (fits all 12 rounds + m102's shape curve): this structure
// scales with resident blocks/CU: 1/CU=320-500 TF, 2/CU=535, 4/CU=~830.
// R0's grid (16,32)=512 blocks grid-caps residency at 2/CU although LDS
// (32KB -> 5/CU) and regs (~100 -> 4/CU) allow 4. Split-K=2 via blockIdx.z
// -> 1024 blocks = 4/CU. Body is byte-identical to the R0-proven kernel;
// z=0 writes Cout, z=1 writes Cpart; float4 add merges (R5/R12-proven).
__global__ __launch_bounds__(256, 2) void gemm_nt_sk(
    const unsigned short* __restrict__ A,  // [M,Ktot] bf16 (g)
    const unsigned short* __restrict__ B,  // [N,Ktot] bf16 (w2)
    float* __restrict__ Cout,              // [M,N] fp32 partial (z=0)
    float* __restrict__ Cpart,             // [M,N] fp32 partial (z=1)
    int M, int N, int Ktot, int kLen) {
  __shared__ unsigned short As[128 * 64];  // 16 KB
  __shared__ unsigned short Bs[128 * 64];  // 16 KB

  const int tid = threadIdx.x;
  const int lane = tid & 63;
  const int wave = tid >> 6;
  const int wm = wave >> 1;       // 0..1
  const int wn = wave & 1;        // 0..1
  const int m0 = blockIdx.y * 128, n0 = blockIdx.x * 128;
  const int kOff = blockIdx.z * kLen;

  int soff[4], sdst[4];
#pragma unroll
  for (int p = 0; p < 4; p++) {
    int u = tid + 256 * p;
    int r = u >> 3;
    int c = ((u & 7) ^ (r & 7)) * 8;
    soff[p] = r * Ktot + c;
    sdst[p] = u * 8;
  }

  const int q = lane >> 4;
  const int r16 = lane & 15;
  const int rx = r16 & 7;

  floatx4 acc[4][4];
#pragma unroll
  for (int i = 0; i < 4; i++)
#pragma unroll
    for (int j = 0; j < 4; j++) acc[i][j] = (floatx4){0.f, 0.f, 0.f, 0.f};

  const unsigned short* Abase = A + (size_t)m0 * Ktot + kOff;
  const unsigned short* Bbase = B + (size_t)n0 * Ktot + kOff;

  for (int k0 = 0; k0 < kLen; k0 += 64) {
#pragma unroll
    for (int p = 0; p < 4; p++) {
      load16_to_lds(Abase + soff[p] + k0, &As[sdst[p]]);
      load16_to_lds(Bbase + soff[p] + k0, &Bs[sdst[p]]);
    }
    __syncthreads();

#pragma unroll
    for (int kh = 0; kh < 2; kh++) {
      const int kq = kh * 4 + q;
      short8 a[4], b[4];
#pragma unroll
      for (int i = 0; i < 4; i++) {
        int row = wm * 64 + i * 16 + r16;
        a[i] = *(const short8*)&As[(row * 8 + (kq ^ rx)) * 8];
      }
#pragma unroll
      for (int j = 0; j < 4; j++) {
        int row = wn * 64 + j * 16 + r16;
        b[j] = *(const short8*)&Bs[(row * 8 + (kq ^ rx)) * 8];
      }
#pragma unroll
      for (int i = 0; i < 4; i++)
#pragma unroll
        for (int j = 0; j < 4; j++)
          acc[i][j] = __builtin_amdgcn_mfma_f32_16x16x32_bf16(
              a[i], b[j], acc[i][j], 0, 0, 0);
    }
    __syncthreads();
  }

  float* C = (blockIdx.z == 0) ? Cout : Cpart;
#pragma unroll
  for (int i = 0; i < 4; i++) {
    int row0 = m0 + wm * 64 + i * 16 + q * 4;
#pragma unroll
    for (int j = 0; j < 4; j++) {
      int col = n0 + wn * 64 + j * 16 + r16;
#pragma unroll
      for (int rr = 0; rr < 4; rr++)
        C[(size_t)(row0 + rr) * N + col] = acc[i][j][rr];
    }
  }
}

// out += part1
__global__ void add_f32_kernel(float* __restrict__ out,
                               const float* __restrict__ p1, long n4) {
  long i = blockIdx.x * (long)blockDim.x + threadIdx.x;
  if (i >= n4) return;
  float4 a = ((const float4*)out)[i];
  float4 b = ((const float4*)p1)[i];
  a.x += b.x; a.y += b.y; a.z += b.z; a.w += b.w;
  ((float4*)out)[i] = a;
}

// ---------- launch ----------
extern "C" void kernel_launch(void* const* d_in, const int* in_sizes, int n_in,
                              void* d_out, int out_size, void* d_ws, size_t ws_size,
                              hipStream_t stream) {
  const float* x = (const float*)d_in[0];
  const float* w1q = (const float*)d_in[1];
  const float* w1s = (const float*)d_in[2];
  const float* w3q = (const float*)d_in[3];
  const float* w3s = (const float*)d_in[4];
  const float* w2q = (const float*)d_in[5];
  const float* w2s = (const float*)d_in[6];

  const int T = 4096, H = 2048, F = 7168;

  char* ws = (char*)d_ws;
  unsigned short* xb  = (unsigned short*)ws;  ws += (size_t)T * H * 2;   // 16.8 MB
  unsigned short* w1b = (unsigned short*)ws;  ws += (size_t)F * H * 2;   // 29.4 MB
  unsigned short* w3b = (unsigned short*)ws;  ws += (size_t)F * H * 2;   // 29.4 MB
  unsigned short* w2b = (unsigned short*)ws;  ws += (size_t)H * F * 2;   // 29.4 MB
  unsigned short* g   = (unsigned short*)ws;  ws += (size_t)T * F * 2;   // 58.7 MB
  // part1 aliases xb+w1b (both dead after dual_gemm_silu; stream-ordered;
  // R5/R12-proven)
  float* part1 = (float*)xb;                                             // 33.5 MB

  long xn4 = (long)T * H / 4;

  f32_to_bf16_kernel<<<(xn4 + 255) / 256, 256, 0, stream>>>(x, xb, xn4);
  dequant2_kernel<<<dim3(H / 1024, F), 256, 0, stream>>>(
      w1q, w1s, w3q, w3s, w1b, w3b, H, H / 128);
  dequant1_kernel<<<dim3(F / 1024, H), 256, 0, stream>>>(
      w2q, w2s, w2b, F, F / 128);

  // g = silu(x @ w1^T) * (x @ w3^T)
  dual_gemm_silu<<<dim3(F / 128, T / 128), 256, 0, stream>>>(xb, w1b, w3b, g, T, F, H);

  // out = g @ w2^T : split-K=2 -> 1024 blocks = 4 resident/CU
  gemm_nt_sk<<<dim3(H / 128, T / 128, 2), 256, 0, stream>>>(
      g, w2b, (float*)d_out, part1, T, H, F, F / 2);

  long on4 = (long)T * H / 4;
  add_f32_kernel<<<(on4 + 255) / 256, 256, 0, stream>>>((float*)d_out, part1, on4);
}